// Round 10
// baseline (597.793 us; speedup 1.0000x reference)
//
#include <hip/hip_runtime.h>
#include <hip/hip_fp16.h>

#define N_USERS 200000
#define N_ITEMS 50000
#define NTOT    250000
#define NNZ     5000000
#define EMB     64
#define BATCH   16384

// ---- two-phase radix build parameters ----
#define EPB_A   16384                        // elements per scatterA block
#define NBLK_A  ((NNZ + EPB_A - 1) / EPB_A)  // 306
#define CB      62                           // coarse buckets: row>>12 (4096 rows)
#define CBP     64                           // padded stride in H1
#define FPB     32                           // fine buckets per coarse (4096/128)
#define NFINE   (CB * FPB)                   // 1984 fine buckets of 128 rows
#define EPB_B   16384                        // elements per phase-B chunk
#define CH_MAX  6                            // chunks per coarse (mean 81920 -> 5; +57 sigma)
#define MAXB    3072                         // max fine-bucket size (mean 2560)

// half4 loaded/stored as one float2 (8 B)
__device__ inline float4 h4_to_f4(float2 raw) {
    __half2 h01 = *(__half2*)&raw.x;
    __half2 h23 = *(__half2*)&raw.y;
    float2 f01 = __half22float2(h01);
    float2 f23 = __half22float2(h23);
    return make_float4(f01.x, f01.y, f23.x, f23.y);
}
__device__ inline float2 f4_to_h4(float4 v) {
    __half2 h01 = __floats2half2_rn(v.x, v.y);
    __half2 h23 = __floats2half2_rn(v.z, v.w);
    float2 raw;
    raw.x = *(float*)&h01;
    raw.y = *(float*)&h23;
    return raw;
}

// ---------------- common kernels ----------------

__global__ void init_cur_h_kernel(const float4* __restrict__ ue4,
                                  const float4* __restrict__ ie4,
                                  float2* __restrict__ curh) {
    int i = blockIdx.x * blockDim.x + threadIdx.x;         // float4 index
    const int n_u4 = N_USERS * 16;
    const int n_t4 = NTOT * 16;
    if (i >= n_t4) return;
    float4 v = (i < n_u4) ? ue4[i] : ie4[i - n_u4];
    curh[i] = f4_to_h4(v);
}

// layer-0 term, exact fp32 straight from inputs (also initializes ub/ib)
__global__ void gather_emb_kernel(const float* __restrict__ ue,
                                  const float* __restrict__ ie,
                                  const int* __restrict__ batch,
                                  float* __restrict__ ub,
                                  float* __restrict__ ib) {
    int t    = blockIdx.x * blockDim.x + threadIdx.x;
    int b    = t >> 6;
    int lane = t & 63;
    if (b >= BATCH) return;
    int ur = batch[2 * b];
    int ir = batch[2 * b + 1];
    ub[(long)b * EMB + lane] = ue[(long)ur * EMB + lane];
    ib[(long)b * EMB + lane] = ie[(long)ir * EMB + lane];
}

__global__ void gather_add_h_kernel(const __half* __restrict__ src,
                                    const int* __restrict__ batch,
                                    float* __restrict__ ub,
                                    float* __restrict__ ib) {
    int t    = blockIdx.x * blockDim.x + threadIdx.x;
    int b    = t >> 6;
    int lane = t & 63;
    if (b >= BATCH) return;
    int ur = batch[2 * b];
    int ir = N_USERS + batch[2 * b + 1];
    ub[(long)b * EMB + lane] += __half2float(src[(long)ur * EMB + lane]);
    ib[(long)b * EMB + lane] += __half2float(src[(long)ir * EMB + lane]);
}

__global__ void dot_kernel(const float* __restrict__ ub,
                           const float* __restrict__ ib,
                           float* __restrict__ out) {
    int t    = blockIdx.x * blockDim.x + threadIdx.x;
    int b    = t >> 6;
    int lane = t & 63;
    if (b >= BATCH) return;
    float p = ub[(long)b * EMB + lane] * ib[(long)b * EMB + lane];
    #pragma unroll
    for (int off = 32; off > 0; off >>= 1)
        p += __shfl_down(p, off, 64);
    if (lane == 0) out[b] = p * (1.0f / 16.0f);
}

// ---------------- atomic-free two-phase radix CSR build ----------------

// A1: per-block LDS histogram over 62 coarse buckets
__global__ void histA_kernel(const int* __restrict__ rows, int* __restrict__ H1) {
    __shared__ int h[CBP];
    int b = blockIdx.x, t = threadIdx.x;
    if (t < CBP) h[t] = 0;
    __syncthreads();
    int s = b * EPB_A;
    int e = s + EPB_A; if (e > NNZ) e = NNZ;
    for (int i = s + t; i < e; i += 256)
        atomicAdd(&h[rows[i] >> 12], 1);
    __syncthreads();
    if (t < CBP) H1[b * CBP + t] = h[t];
}

// A2: exclusive scan of each H1 column (over blocks); ctot1[k] = column sum
__global__ void col_scanA_kernel(int* __restrict__ H1, int* __restrict__ ctot1) {
    __shared__ int s[256];
    int k = blockIdx.x;       // coarse bucket
    int t = threadIdx.x;
    int v[2]; int tsum = 0;
    #pragma unroll
    for (int j = 0; j < 2; ++j) {
        int b = t * 2 + j;
        v[j] = (b < NBLK_A) ? H1[b * CBP + k] : 0;
        tsum += v[j];
    }
    s[t] = tsum;
    __syncthreads();
    for (int off = 1; off < 256; off <<= 1) {
        int x = s[t];
        int y = (t >= off) ? s[t - off] : 0;
        __syncthreads();
        s[t] = x + y;
        __syncthreads();
    }
    int run = (t == 0) ? 0 : s[t - 1];
    #pragma unroll
    for (int j = 0; j < 2; ++j) {
        int b = t * 2 + j;
        if (b < NBLK_A) { H1[b * CBP + k] = run; run += v[j]; }
    }
    if (t == 255) ctot1[k] = s[255];
}

// A3: exclusive scan over coarse totals -> cbase1[0..CB]; also rowptr[NTOT]=NNZ
__global__ void scanA_kernel(const int* __restrict__ ctot1,
                             int* __restrict__ cbase1,
                             int* __restrict__ rowptr) {
    __shared__ int s[256];
    int t = threadIdx.x;
    int v = (t < CB) ? ctot1[t] : 0;
    s[t] = v;
    __syncthreads();
    for (int off = 1; off < 256; off <<= 1) {
        int x = s[t];
        int y = (t >= off) ? s[t - off] : 0;
        __syncthreads();
        s[t] = x + y;
        __syncthreads();
    }
    if (t < CB) cbase1[t] = s[t] - v;
    if (t == 0) { cbase1[CB] = NNZ; rowptr[NTOT] = NNZ; }
}

// A4: coarse scatter. Runs of ~256 contiguous elems per (block,coarse).
// pack: col (18b) | (row & 4095) << 18   (30 bits)
__global__ void scatterA_kernel(const int* __restrict__ rows,
                                const int* __restrict__ cols,
                                const float* __restrict__ vals,
                                const int* __restrict__ H1,
                                const int* __restrict__ cbase1,
                                int* __restrict__ pk1,
                                float* __restrict__ pv1) {
    __shared__ int bb[CBP], h[CBP];
    int b = blockIdx.x, t = threadIdx.x;
    if (t < CB) { bb[t] = cbase1[t] + H1[b * CBP + t]; h[t] = 0; }
    __syncthreads();
    int s = b * EPB_A;
    int e = s + EPB_A; if (e > NNZ) e = NNZ;
    for (int i = s + t; i < e; i += 256) {
        int r = rows[i];
        int k = r >> 12;
        int rank = atomicAdd(&h[k], 1);      // LDS atomic
        int pos  = bb[k] + rank;
        pk1[pos] = cols[i] | ((r & 4095) << 18);
        pv1[pos] = vals[i];
    }
}

// B1: per-(coarse,chunk) LDS histogram over 32 fine buckets
__global__ void histB_kernel(const int* __restrict__ pk1,
                             const int* __restrict__ cbase1,
                             int* __restrict__ H2) {
    __shared__ int h[FPB];
    int bid = blockIdx.x;                    // c*CH_MAX + j
    int c = bid / CH_MAX, j = bid % CH_MAX;
    int t = threadIdx.x;
    if (t < FPB) h[t] = 0;
    __syncthreads();
    int cs = cbase1[c], ce = cbase1[c + 1];
    int s = cs + j * EPB_B;
    int e = s + EPB_B; if (e > ce) e = ce;
    for (int i = s + t; i < e; i += 256)
        atomicAdd(&h[(pk1[i] >> 25) & 31], 1);
    __syncthreads();
    if (t < FPB) H2[bid * FPB + t] = h[t];
}

// B2: per coarse: chunk-scan + fine-scan -> H2 holds global bases; cbase2 = fine bases
__global__ void scanB_kernel(const int* __restrict__ cbase1,
                             int* __restrict__ H2,
                             int* __restrict__ cbase2) {
    __shared__ int tot[FPB], fb[FPB];
    int c = blockIdx.x, t = threadIdx.x;
    if (t < FPB) {
        int run = 0;
        for (int j = 0; j < CH_MAX; ++j) {
            int idx = (c * CH_MAX + j) * FPB + t;
            int tmp = H2[idx]; H2[idx] = run; run += tmp;
        }
        tot[t] = run;
    }
    __syncthreads();
    if (t == 0) {
        int run = cbase1[c];
        for (int k = 0; k < FPB; ++k) { fb[k] = run; run += tot[k]; }
    }
    __syncthreads();
    if (t < FPB) {
        cbase2[c * FPB + t] = fb[t];
        for (int j = 0; j < CH_MAX; ++j)
            H2[(c * CH_MAX + j) * FPB + t] += fb[t];
    }
    if (c == CB - 1 && t == 0) cbase2[NFINE] = NNZ;
}

// B3: fine scatter within coarse regions. Runs of ~512 contiguous elems.
__global__ void scatterB_kernel(const int* __restrict__ pk1,
                                const float* __restrict__ pv1,
                                const int* __restrict__ cbase1,
                                const int* __restrict__ H2,
                                int* __restrict__ pk2,
                                float* __restrict__ pv2) {
    __shared__ int bb[FPB], h[FPB];
    int bid = blockIdx.x;
    int c = bid / CH_MAX, j = bid % CH_MAX;
    int t = threadIdx.x;
    if (t < FPB) { bb[t] = H2[bid * FPB + t]; h[t] = 0; }
    __syncthreads();
    int cs = cbase1[c], ce = cbase1[c + 1];
    int s = cs + j * EPB_B;
    int e = s + EPB_B; if (e > ce) e = ce;
    for (int i = s + t; i < e; i += 256) {
        int   w = pk1[i];
        float f = pv1[i];
        int k = (w >> 25) & 31;
        int rank = atomicAdd(&h[k], 1);      // LDS atomic
        int pos  = bb[k] + rank;
        pk2[pos] = w;
        pv2[pos] = f;
    }
}

// C: one block per fine bucket: LDS counting sort over 128 rows -> rowptr + final CSR
__global__ void bucket_sort_kernel(const int* __restrict__ cbase2,
                                   const int* __restrict__ pk2,
                                   const float* __restrict__ pv2,
                                   int* __restrict__ rowptr,
                                   int* __restrict__ pcol,
                                   float* __restrict__ pval) {
    __shared__ int   eL[MAXB];
    __shared__ float vL[MAXB];
    __shared__ int   cnt[128], sc[128], ofs[128];
    int g = blockIdx.x, t = threadIdx.x;
    int s = cbase2[g];
    int e = cbase2[g + 1];
    int n = e - s;
    if (t < 128) cnt[t] = 0;
    __syncthreads();
    for (int i = t; i < n; i += 256) {
        int   w = pk2[s + i];
        float f = pv2[s + i];
        if (i < MAXB) { eL[i] = w; vL[i] = f; }
        atomicAdd(&cnt[(w >> 18) & 127], 1);
    }
    __syncthreads();
    if (t < 128) sc[t] = cnt[t];
    __syncthreads();
    for (int off = 1; off < 128; off <<= 1) {
        int x = 0;
        if (t < 128) { x = sc[t]; if (t >= off) x += sc[t - off]; }
        __syncthreads();
        if (t < 128) sc[t] = x;
        __syncthreads();
    }
    if (t < 128) {
        int rs = sc[t] - cnt[t];
        ofs[t] = rs;
        int r = (g << 7) + t;
        if (r < NTOT) rowptr[r] = s + rs;
    }
    __syncthreads();
    for (int i = t; i < n; i += 256) {
        int w; float f;
        if (i < MAXB) { w = eL[i]; f = vL[i]; }
        else          { w = pk2[s + i]; f = pv2[s + i]; }
        int r7 = (w >> 18) & 127;
        int p  = atomicAdd(&ofs[r7], 1);     // LDS atomic
        pcol[s + p] = w & 0x3FFFF;
        pval[s + p] = f;
    }
}

// ---------------- SpMM (half): 4 rows/wave, 16 lanes/row, half4 gather -------

__global__ void spmm_csr_qh_kernel(const int* __restrict__ rowptr,
                                   const int* __restrict__ pcol,
                                   const float* __restrict__ pval,
                                   const float2* __restrict__ curh,
                                   float2* __restrict__ nexth) {
    int t    = blockIdx.x * blockDim.x + threadIdx.x;
    int wid  = t >> 6;
    int lane = t & 63;
    int q    = lane >> 4;
    int li   = lane & 15;
    int r    = wid * 4 + q;
    if (r >= NTOT) return;
    int s = rowptr[r];
    int e = rowptr[r + 1];
    float4 a0 = make_float4(0.f, 0.f, 0.f, 0.f);
    float4 a1 = make_float4(0.f, 0.f, 0.f, 0.f);
    float4 a2 = make_float4(0.f, 0.f, 0.f, 0.f);
    float4 a3 = make_float4(0.f, 0.f, 0.f, 0.f);
    int k = s;
    for (; k + 4 <= e; k += 4) {
        int   c0 = pcol[k];
        int   c1 = pcol[k + 1];
        int   c2 = pcol[k + 2];
        int   c3 = pcol[k + 3];
        float v0 = pval[k];
        float v1 = pval[k + 1];
        float v2 = pval[k + 2];
        float v3 = pval[k + 3];
        float4 x0 = h4_to_f4(curh[c0 * 16 + li]);
        float4 x1 = h4_to_f4(curh[c1 * 16 + li]);
        float4 x2 = h4_to_f4(curh[c2 * 16 + li]);
        float4 x3 = h4_to_f4(curh[c3 * 16 + li]);
        a0.x += v0 * x0.x; a0.y += v0 * x0.y; a0.z += v0 * x0.z; a0.w += v0 * x0.w;
        a1.x += v1 * x1.x; a1.y += v1 * x1.y; a1.z += v1 * x1.z; a1.w += v1 * x1.w;
        a2.x += v2 * x2.x; a2.y += v2 * x2.y; a2.z += v2 * x2.z; a2.w += v2 * x2.w;
        a3.x += v3 * x3.x; a3.y += v3 * x3.y; a3.z += v3 * x3.z; a3.w += v3 * x3.w;
    }
    for (; k < e; ++k) {
        int   c0 = pcol[k];
        float v0 = pval[k];
        float4 x0 = h4_to_f4(curh[c0 * 16 + li]);
        a0.x += v0 * x0.x; a0.y += v0 * x0.y; a0.z += v0 * x0.z; a0.w += v0 * x0.w;
    }
    float4 o;
    o.x = (a0.x + a1.x) + (a2.x + a3.x);
    o.y = (a0.y + a1.y) + (a2.y + a3.y);
    o.z = (a0.z + a1.z) + (a2.z + a3.z);
    o.w = (a0.w + a1.w) + (a2.w + a3.w);
    nexth[r * 16 + li] = f4_to_h4(o);
}

__global__ void spmv_batch_h_kernel(const int* __restrict__ rowptr,
                                    const int* __restrict__ pcol,
                                    const float* __restrict__ pval,
                                    const int* __restrict__ batch,
                                    const float2* __restrict__ curh,
                                    float4* __restrict__ ub4,
                                    float4* __restrict__ ib4) {
    int t    = blockIdx.x * blockDim.x + threadIdx.x;
    int wid  = t >> 6;
    int lane = t & 63;
    int q    = lane >> 4;
    int li   = lane & 15;
    int idx  = wid * 4 + q;
    if (idx >= 2 * BATCH) return;
    int b = idx & (BATCH - 1);
    int r;
    float4* dst;
    if (idx < BATCH) { r = batch[2 * b];               dst = ub4; }
    else             { r = N_USERS + batch[2 * b + 1]; dst = ib4; }
    int s = rowptr[r];
    int e = rowptr[r + 1];
    float4 a0 = make_float4(0.f, 0.f, 0.f, 0.f);
    float4 a1 = make_float4(0.f, 0.f, 0.f, 0.f);
    float4 a2 = make_float4(0.f, 0.f, 0.f, 0.f);
    float4 a3 = make_float4(0.f, 0.f, 0.f, 0.f);
    int k = s;
    for (; k + 4 <= e; k += 4) {
        int   c0 = pcol[k];
        int   c1 = pcol[k + 1];
        int   c2 = pcol[k + 2];
        int   c3 = pcol[k + 3];
        float v0 = pval[k];
        float v1 = pval[k + 1];
        float v2 = pval[k + 2];
        float v3 = pval[k + 3];
        float4 x0 = h4_to_f4(curh[c0 * 16 + li]);
        float4 x1 = h4_to_f4(curh[c1 * 16 + li]);
        float4 x2 = h4_to_f4(curh[c2 * 16 + li]);
        float4 x3 = h4_to_f4(curh[c3 * 16 + li]);
        a0.x += v0 * x0.x; a0.y += v0 * x0.y; a0.z += v0 * x0.z; a0.w += v0 * x0.w;
        a1.x += v1 * x1.x; a1.y += v1 * x1.y; a1.z += v1 * x1.z; a1.w += v1 * x1.w;
        a2.x += v2 * x2.x; a2.y += v2 * x2.y; a2.z += v2 * x2.z; a2.w += v2 * x2.w;
        a3.x += v3 * x3.x; a3.y += v3 * x3.y; a3.z += v3 * x3.z; a3.w += v3 * x3.w;
    }
    for (; k < e; ++k) {
        int   c0 = pcol[k];
        float v0 = pval[k];
        float4 x0 = h4_to_f4(curh[c0 * 16 + li]);
        a0.x += v0 * x0.x; a0.y += v0 * x0.y; a0.z += v0 * x0.z; a0.w += v0 * x0.w;
    }
    float4 p = dst[b * 16 + li];
    p.x += (a0.x + a1.x) + (a2.x + a3.x);
    p.y += (a0.y + a1.y) + (a2.y + a3.y);
    p.z += (a0.z + a1.z) + (a2.z + a3.z);
    p.w += (a0.w + a1.w) + (a2.w + a3.w);
    dst[b * 16 + li] = p;
}

// ---------------- fallback fp32 atomic path (small-ws) ----------------

__global__ void init_cur_kernel(const float* __restrict__ ue,
                                const float* __restrict__ ie,
                                float* __restrict__ cur) {
    long i = (long)blockIdx.x * blockDim.x + threadIdx.x;
    const long n_u4 = (long)N_USERS * EMB / 4;
    const long n_t4 = (long)NTOT * EMB / 4;
    if (i < n_u4) {
        ((float4*)cur)[i] = ((const float4*)ue)[i];
    } else if (i < n_t4) {
        ((float4*)cur)[i] = ((const float4*)ie)[i - n_u4];
    }
}

__global__ void gather_add_kernel(const float* __restrict__ src,
                                  const int* __restrict__ batch,
                                  float* __restrict__ ub,
                                  float* __restrict__ ib) {
    int t    = blockIdx.x * blockDim.x + threadIdx.x;
    int b    = t >> 6;
    int lane = t & 63;
    if (b >= BATCH) return;
    int ur = batch[2 * b];
    int ir = N_USERS + batch[2 * b + 1];
    ub[(long)b * EMB + lane] += src[(long)ur * EMB + lane];
    ib[(long)b * EMB + lane] += src[(long)ir * EMB + lane];
}

__global__ void spmm_atomic_kernel(const int* __restrict__ rows,
                                   const int* __restrict__ cols,
                                   const float* __restrict__ vals,
                                   const float* __restrict__ cur,
                                   float* __restrict__ next) {
    int t    = blockIdx.x * blockDim.x + threadIdx.x;
    int nz   = t >> 6;
    int lane = t & 63;
    if (nz >= NNZ) return;
    int   r = rows[nz];
    int   c = cols[nz];
    float v = vals[nz];
    float x = cur[(long)c * EMB + lane];
    atomicAdd(&next[(long)r * EMB + lane], v * x);
}

// ---------------- launch ----------------

extern "C" void kernel_launch(void* const* d_in, const int* in_sizes, int n_in,
                              void* d_out, int out_size, void* d_ws, size_t ws_size,
                              hipStream_t stream) {
    const float* ue    = (const float*)d_in[0];
    const float* ie    = (const float*)d_in[1];
    const int*   rows  = (const int*)d_in[2];
    const int*   cols  = (const int*)d_in[3];
    const float* vals  = (const float*)d_in[4];
    const int*   batch = (const int*)d_in[5];
    float*       out   = (float*)d_out;

    const size_t HEMB_BYTES = (size_t)NTOT * EMB * sizeof(__half);  // 32,000,000
    const size_t BUF_BYTES  = (size_t)BATCH * EMB * sizeof(float);  // 4,194,304
    const size_t NZI_BYTES  = (size_t)NNZ * sizeof(int);            // 20,000,000
    const size_t PTR_BYTES  = ((size_t)(NTOT + 1) * sizeof(int) + 255) & ~(size_t)255;
    const size_t H1_BYTES   = ((size_t)NBLK_A * CBP * sizeof(int) + 255) & ~(size_t)255;
    const size_t H2_BYTES   = ((size_t)CB * CH_MAX * FPB * sizeof(int) + 255) & ~(size_t)255;
    const size_t SB_BYTES   = 16384;  // ctot1 + cbase1 + cbase2 region

    char* ws = (char*)d_ws;
    size_t off = 0;
    float2* curh  = (float2*)(ws + off); off += HEMB_BYTES;
    float2* nxth  = (float2*)(ws + off); off += HEMB_BYTES;
    float*  ub    = (float*)(ws + off);  off += BUF_BYTES;
    float*  ib    = (float*)(ws + off);  off += BUF_BYTES;   // ub,ib contiguous
    int*    bufAk = (int*)(ws + off);    off += NZI_BYTES;   // scatterA out -> final pcol
    float*  bufAv = (float*)(ws + off);  off += NZI_BYTES;   // scatterA out -> final pval
    int*    bufBk = (int*)(ws + off);    off += NZI_BYTES;   // scatterB out, sort in
    float*  bufBv = (float*)(ws + off);  off += NZI_BYTES;
    int*    rowptr= (int*)(ws + off);    off += PTR_BYTES;
    int*    H1    = (int*)(ws + off);    off += H1_BYTES;
    int*    H2    = (int*)(ws + off);    off += H2_BYTES;
    int*    ctot1 = (int*)(ws + off);
    int*    cbase1= ctot1 + 256;
    int*    cbase2= ctot1 + 512;         off += SB_BYTES;
    const size_t NEEDED_CSR = off;       // ~154 MB

    if (ws_size >= NEEDED_CSR) {
        // 1) half cur = concat(emb); layer-0 term exact from fp32 inputs
        init_cur_h_kernel<<<(NTOT * 16 + 255) / 256, 256, 0, stream>>>(
            (const float4*)ue, (const float4*)ie, curh);
        gather_emb_kernel<<<(BATCH * 64) / 256, 256, 0, stream>>>(ue, ie, batch, ub, ib);

        // 2) two-phase radix CSR build (long-run scatters, no global atomics)
        histA_kernel<<<NBLK_A, 256, 0, stream>>>(rows, H1);
        col_scanA_kernel<<<CB, 256, 0, stream>>>(H1, ctot1);
        scanA_kernel<<<1, 256, 0, stream>>>(ctot1, cbase1, rowptr);
        scatterA_kernel<<<NBLK_A, 256, 0, stream>>>(rows, cols, vals, H1, cbase1,
                                                    bufAk, bufAv);
        histB_kernel<<<CB * CH_MAX, 256, 0, stream>>>(bufAk, cbase1, H2);
        scanB_kernel<<<CB, 64, 0, stream>>>(cbase1, H2, cbase2);
        scatterB_kernel<<<CB * CH_MAX, 256, 0, stream>>>(bufAk, bufAv, cbase1, H2,
                                                         bufBk, bufBv);
        bucket_sort_kernel<<<NFINE, 256, 0, stream>>>(cbase2, bufBk, bufBv,
                                                      rowptr, bufAk, bufAv);
        int* pcolF  = bufAk;   // final CSR
        float* pvalF= bufAv;

        // 3) layers 1,2 full (half); layer 3 only at batch rows
        float2* c = curh; float2* n = nxth;
        for (int l = 0; l < 2; ++l) {
            spmm_csr_qh_kernel<<<(NTOT / 4 * 64) / 256, 256, 0, stream>>>(
                rowptr, pcolF, pvalF, c, n);
            gather_add_h_kernel<<<(BATCH * 64) / 256, 256, 0, stream>>>(
                (const __half*)n, batch, ub, ib);
            float2* tmp = c; c = n; n = tmp;
        }
        spmv_batch_h_kernel<<<(2 * BATCH / 4 * 64) / 256, 256, 0, stream>>>(
            rowptr, pcolF, pvalF, batch, c, (float4*)ub, (float4*)ib);
    } else {
        // fallback: fp32 atomic path (independent layout, 136.4 MB)
        const size_t EMB_BYTES = (size_t)NTOT * EMB * sizeof(float);
        float* cur = (float*)ws;
        float* nxt = (float*)(ws + EMB_BYTES);
        float* ub2 = (float*)(ws + 2 * EMB_BYTES);
        float* ib2 = (float*)(ws + 2 * EMB_BYTES + BUF_BYTES);
        int n_t4 = NTOT * (EMB / 4);
        init_cur_kernel<<<(n_t4 + 255) / 256, 256, 0, stream>>>(ue, ie, cur);
        hipMemsetAsync(ub2, 0, 2 * BUF_BYTES, stream);
        gather_add_kernel<<<(BATCH * 64) / 256, 256, 0, stream>>>(cur, batch, ub2, ib2);
        for (int l = 0; l < 3; ++l) {
            hipMemsetAsync(nxt, 0, EMB_BYTES, stream);
            spmm_atomic_kernel<<<NNZ / 4, 256, 0, stream>>>(rows, cols, vals, cur, nxt);
            gather_add_kernel<<<(BATCH * 64) / 256, 256, 0, stream>>>(nxt, batch, ub2, ib2);
            float* tmp = cur; cur = nxt; nxt = tmp;
        }
        dot_kernel<<<(BATCH * 64) / 256, 256, 0, stream>>>(ub2, ib2, out);
        return;
    }

    // 4) score
    dot_kernel<<<(BATCH * 64) / 256, 256, 0, stream>>>(ub, ib, out);
}